// Round 10
// baseline (268.805 us; speedup 1.0000x reference)
//
#include <hip/hip_runtime.h>

// Problem constants: B=2, T=2048, D=1024, H=16, DH=64
#define T_SEQ 2048
#define DMODEL 1024
#define NHEAD 16
#define MROWS 4096          // B*T
#define N_QKV 3072          // 3*D
#define LDT 72              // attn K/V LDS row stride (elements), padded
#define LDP 68              // attn P LDS row stride: 136B/row -> P b16 writes 2 lanes/bank (free)
#define LDG 64              // GEMM LDS row stride: LINEAR (global_load_lds requires contiguous dest)

typedef float f32x4 __attribute__((ext_vector_type(4)));
typedef __bf16 bf16_t;
typedef bf16_t bf16x8 __attribute__((ext_vector_type(8)));

// native f32->bf16 (RNE); compiler packs pairs into v_cvt_pk_bf16_f32 (m240)
__device__ __forceinline__ unsigned short f2bf(float f) {
  return __builtin_bit_cast(unsigned short, (__bf16)f);
}

__device__ __forceinline__ f32x4 mfma16(bf16x8 a, bf16x8 b, f32x4 c) {
  return __builtin_amdgcn_mfma_f32_16x16x32_bf16(a, b, c, 0, 0, 0);
}

// async global->LDS, 16B per lane. LDS dest must be wave-uniform base + lane*16,
// which our (row=tid>>3, col=(tid&7)*8) mapping onto a linear [*][64] tile satisfies.
__device__ __forceinline__ void gload_lds16(const unsigned short* gsrc, unsigned short* ldst) {
  __builtin_amdgcn_global_load_lds(
      (const __attribute__((address_space(1))) unsigned int*)gsrc,
      (__attribute__((address_space(3))) unsigned int*)ldst,
      16, 0, 0);
}

// ---------------- LayerNorm: x[4096][1024] f32 -> h bf16 ----------------
__global__ __launch_bounds__(256) void ln_kernel(const float* __restrict__ x,
    const float* __restrict__ g, const float* __restrict__ be,
    unsigned short* __restrict__ h) {
  int row = blockIdx.x;
  int t = threadIdx.x;
  float4 v = reinterpret_cast<const float4*>(x + (size_t)row * DMODEL)[t];
  float s = v.x + v.y + v.z + v.w;
  float s2 = v.x * v.x + v.y * v.y + v.z * v.z + v.w * v.w;
  for (int m = 1; m < 64; m <<= 1) { s += __shfl_xor(s, m, 64); s2 += __shfl_xor(s2, m, 64); }
  __shared__ float ls[4], ls2[4];
  int w = t >> 6;
  if ((t & 63) == 0) { ls[w] = s; ls2[w] = s2; }
  __syncthreads();
  s = ls[0] + ls[1] + ls[2] + ls[3];
  s2 = ls2[0] + ls2[1] + ls2[2] + ls2[3];
  float mean = s * (1.0f / DMODEL);
  float var = s2 * (1.0f / DMODEL) - mean * mean;   // biased var, matches jnp.var
  float rstd = rsqrtf(var + 1e-3f);
  float4 gv = reinterpret_cast<const float4*>(g)[t];
  float4 bv = reinterpret_cast<const float4*>(be)[t];
  ushort4 o;
  o.x = f2bf((v.x - mean) * rstd * gv.x + bv.x);
  o.y = f2bf((v.y - mean) * rstd * gv.y + bv.y);
  o.z = f2bf((v.z - mean) * rstd * gv.z + bv.z);
  o.w = f2bf((v.w - mean) * rstd * gv.w + bv.w);
  reinterpret_cast<ushort4*>(h + (size_t)row * DMODEL)[t] = o;
}

// ------------- transpose+cast: in f32 [rows][cols] -> out bf16 [cols][rows] -------------
__global__ __launch_bounds__(256) void transpose_cast(const float* __restrict__ in,
    unsigned short* __restrict__ out, int rows, int cols) {
  __shared__ float tile[32][33];
  int c0 = blockIdx.x * 32, r0 = blockIdx.y * 32;
  int tx = threadIdx.x & 31, ty = threadIdx.x >> 5;
  #pragma unroll
  for (int i = 0; i < 4; ++i) {
    int r = ty + i * 8;
    tile[r][tx] = in[(size_t)(r0 + r) * cols + c0 + tx];
  }
  __syncthreads();
  #pragma unroll
  for (int i = 0; i < 4; ++i) {
    int r = ty + i * 8;
    out[(size_t)(c0 + r) * rows + r0 + tx] = f2bf(tile[tx][r]);
  }
}

// ------------- vtrans: V part of qkv [b,t,(h d)] -> vT [b,h,d,t] (bf16->bf16) -------------
__global__ __launch_bounds__(256) void vtrans_kernel(const unsigned short* __restrict__ qkv,
    unsigned short* __restrict__ vT) {
  int bh = blockIdx.y;
  int b = bh >> 4, h = bh & 15;
  int t0 = blockIdx.x * 64;
  __shared__ alignas(16) unsigned short tile[64 * LDT];
  int tid = threadIdx.x;
  const unsigned short* src = qkv + (size_t)b * T_SEQ * N_QKV + 2 * DMODEL + h * 64;
  #pragma unroll
  for (int it = 0; it < 2; ++it) {
    int cid = it * 256 + tid;
    int i = cid >> 3, c8 = cid & 7;           // row i of tile, 16B chunk c8
    ulonglong2 v = *reinterpret_cast<const ulonglong2*>(src + (size_t)(t0 + i) * N_QKV + c8 * 8);
    *reinterpret_cast<ulonglong2*>(&tile[i * LDT + ((c8 ^ (i >> 3)) & 7) * 8]) = v;
  }
  __syncthreads();
  unsigned short* dst = vT + (size_t)bh * 64 * T_SEQ;
  #pragma unroll
  for (int it = 0; it < 2; ++it) {
    int cid = it * 256 + tid;
    int d = cid >> 3, t8 = cid & 7;           // output row d, 8 t-values starting t8*8
    unsigned short vals[8];
    #pragma unroll
    for (int e = 0; e < 8; ++e) {
      int t = t8 * 8 + e;
      vals[e] = tile[t * LDT + ((((d >> 3) ^ (t >> 3)) & 7) * 8 + (d & 7))];
    }
    *reinterpret_cast<ulonglong2*>(dst + (size_t)d * T_SEQ + t0 + t8 * 8) =
        *reinterpret_cast<ulonglong2*>(vals);
  }
}

// ------------- GEMM: C[M][N] = A[M][K] @ Bt[N][K]^T, bf16 in, bf16 out -------------
__global__ __launch_bounds__(256) void gemm_bt_bf16(
    const unsigned short* __restrict__ A, const unsigned short* __restrict__ Bt,
    unsigned short* __restrict__ C, int Mdim, int Ndim, int Kdim) {
  __shared__ alignas(16) unsigned short Alds[128 * LDG];
  __shared__ alignas(16) unsigned short Blds[128 * LDG];
  int tid = threadIdx.x;
  int wid = tid >> 6, lane = tid & 63;
  int l15 = lane & 15, l4 = lane >> 4;
  int m0 = blockIdx.y * 128, n0 = blockIdx.x * 128;
  int wm = (wid >> 1) * 64, wn = (wid & 1) * 64;
  f32x4 acc[4][4] = {};
  int crow = tid >> 3, ccol = (tid & 7) * 8;
  for (int k0 = 0; k0 < Kdim; k0 += 64) {
    __syncthreads();   // WAR: prior tile's ds_reads done before overwrite
    #pragma unroll
    for (int it = 0; it < 4; ++it) {
      int row = crow + it * 32;
      gload_lds16(A + (size_t)(m0 + row) * Kdim + k0 + ccol, &Alds[row * LDG + ccol]);
      gload_lds16(Bt + (size_t)(n0 + row) * Kdim + k0 + ccol, &Blds[row * LDG + ccol]);
    }
    __syncthreads();   // drains vmcnt(0): staged tile visible
    #pragma unroll
    for (int ks = 0; ks < 2; ++ks) {
      int co = ks * 32 + l4 * 8;
      bf16x8 af[4], bfr[4];
      #pragma unroll
      for (int i = 0; i < 4; ++i)
        af[i] = *reinterpret_cast<const bf16x8*>(&Alds[(wm + i * 16 + l15) * LDG + co]);
      #pragma unroll
      for (int j = 0; j < 4; ++j)
        bfr[j] = *reinterpret_cast<const bf16x8*>(&Blds[(wn + j * 16 + l15) * LDG + co]);
      #pragma unroll
      for (int i = 0; i < 4; ++i)
        #pragma unroll
        for (int j = 0; j < 4; ++j)
          acc[i][j] = mfma16(af[i], bfr[j], acc[i][j]);
    }
  }
  #pragma unroll
  for (int i = 0; i < 4; ++i)
    #pragma unroll
    for (int j = 0; j < 4; ++j)
      #pragma unroll
      for (int r = 0; r < 4; ++r) {
        int rr = m0 + wm + i * 16 + l4 * 4 + r;
        int cc = n0 + wn + j * 16 + l15;
        C[(size_t)rr * Ndim + cc] = f2bf(acc[i][j][r]);
      }
}

// ------------- GEMM + residual: C f32 = A @ Bt^T + resid -------------
__global__ __launch_bounds__(256) void gemm_bt_f32res(
    const unsigned short* __restrict__ A, const unsigned short* __restrict__ Bt,
    float* __restrict__ C, const float* __restrict__ resid,
    int Mdim, int Ndim, int Kdim) {
  __shared__ alignas(16) unsigned short Alds[128 * LDG];
  __shared__ alignas(16) unsigned short Blds[128 * LDG];
  int tid = threadIdx.x;
  int wid = tid >> 6, lane = tid & 63;
  int l15 = lane & 15, l4 = lane >> 4;
  int m0 = blockIdx.y * 128, n0 = blockIdx.x * 128;
  int wm = (wid >> 1) * 64, wn = (wid & 1) * 64;
  f32x4 acc[4][4] = {};
  int crow = tid >> 3, ccol = (tid & 7) * 8;
  for (int k0 = 0; k0 < Kdim; k0 += 64) {
    __syncthreads();
    #pragma unroll
    for (int it = 0; it < 4; ++it) {
      int row = crow + it * 32;
      gload_lds16(A + (size_t)(m0 + row) * Kdim + k0 + ccol, &Alds[row * LDG + ccol]);
      gload_lds16(Bt + (size_t)(n0 + row) * Kdim + k0 + ccol, &Blds[row * LDG + ccol]);
    }
    __syncthreads();
    #pragma unroll
    for (int ks = 0; ks < 2; ++ks) {
      int co = ks * 32 + l4 * 8;
      bf16x8 af[4], bfr[4];
      #pragma unroll
      for (int i = 0; i < 4; ++i)
        af[i] = *reinterpret_cast<const bf16x8*>(&Alds[(wm + i * 16 + l15) * LDG + co]);
      #pragma unroll
      for (int j = 0; j < 4; ++j)
        bfr[j] = *reinterpret_cast<const bf16x8*>(&Blds[(wn + j * 16 + l15) * LDG + co]);
      #pragma unroll
      for (int i = 0; i < 4; ++i)
        #pragma unroll
        for (int j = 0; j < 4; ++j)
          acc[i][j] = mfma16(af[i], bfr[j], acc[i][j]);
    }
  }
  #pragma unroll
  for (int i = 0; i < 4; ++i)
    #pragma unroll
    for (int j = 0; j < 4; ++j)
      #pragma unroll
      for (int r = 0; r < 4; ++r) {
        size_t idx = (size_t)(m0 + wm + i * 16 + l4 * 4 + r) * Ndim + n0 + wn + j * 16 + l15;
        C[idx] = resid[idx] + acc[i][j][r];
      }
}

// ------------- fused flash attention: static-max softmax, K/V dbuf, 1 barrier/iter -------------
// grid 1024, XCD-decoded (4 bh per XCD; K/V set 2MB fits per-XCD L2). 16 q-rows/wave.
// LDS 45.6KB -> 3 blocks/CU (12 waves/CU) for MFMA||VALU cross-wave overlap.
// Double-buffered K/V: iter t reads buf[t&1], writes buf[t&1^1] (tile t+1, from regs
// loaded in iter t-1) -> ONE barrier per iter (at end) covers RAW+WAR; T14 loads get
// a full iter to land. P is per-wave-private LDS (in-order DS ops, no barrier needed),
// stride LDP=68 -> b16 P-writes hit 32 banks at 2 lanes/bank (free).
__global__ __launch_bounds__(256) void attn_kernel(const unsigned short* __restrict__ qkv,
    const unsigned short* __restrict__ vT, unsigned short* __restrict__ o) {
  int flat = blockIdx.x;
  int xcd = flat & 7, idx = flat >> 3;          // 128 idx per XCD
  int bh = xcd * 4 + (idx >> 5);                // 4 bh per XCD
  int q0 = (idx & 31) * 64;
  int b = bh >> 4, h = bh & 15;
  int tid = threadIdx.x, wid = tid >> 6, lane = tid & 63;
  int l15 = lane & 15, l4 = lane >> 4;
  __shared__ alignas(16) unsigned short Klds[2][64 * LDT];   // K[j][d], double-buffered
  __shared__ alignas(16) unsigned short Vlds[2][64 * LDT];   // V^T[d][j], double-buffered
  __shared__ alignas(16) unsigned short Plds[4][16 * LDP];   // per-wave P
  const unsigned short* base = qkv + (size_t)b * T_SEQ * N_QKV;
  const unsigned short* vbase = vT + (size_t)bh * 64 * T_SEQ;

  // Q fragments in registers, pre-scaled by 0.125*log2(e) (exp2 domain)
  bf16x8 qf[2];
  {
    const unsigned short* qrow = base + (size_t)(q0 + wid * 16 + l15) * N_QKV + h * 64;
    qf[0] = *reinterpret_cast<const bf16x8*>(qrow + l4 * 8);
    qf[1] = *reinterpret_cast<const bf16x8*>(qrow + 32 + l4 * 8);
    #pragma unroll
    for (int e = 0; e < 8; ++e) {
      qf[0][e] = (__bf16)((float)qf[0][e] * 0.18033688f);
      qf[1][e] = (__bf16)((float)qf[1][e] * 0.18033688f);
    }
  }
  bf16x8 ones;
  #pragma unroll
  for (int e = 0; e < 8; ++e) ones[e] = (__bf16)1.0f;

  f32x4 accO[4] = {};
  f32x4 accL = {};

  int crow = tid >> 3, ccol8 = tid & 7;
  const unsigned short* kp0 = base + (size_t)crow * N_QKV + DMODEL + h * 64 + ccol8 * 8;
  const unsigned short* kp1 = kp0 + (size_t)32 * N_QKV;
  const unsigned short* vp0 = vbase + (size_t)crow * T_SEQ + ccol8 * 8;
  const unsigned short* vp1 = vp0 + (size_t)32 * T_SEQ;
  int ko0 = crow * LDT + ccol8 * 8;          // LDS offsets within one buffer
  int ko1 = (crow + 32) * LDT + ccol8 * 8;

  // prologue: tile 0 -> regs -> buf0; then issue tile 1 loads
  ulonglong2 rk0 = *reinterpret_cast<const ulonglong2*>(kp0);
  ulonglong2 rk1 = *reinterpret_cast<const ulonglong2*>(kp1);
  ulonglong2 rv0 = *reinterpret_cast<const ulonglong2*>(vp0);
  ulonglong2 rv1 = *reinterpret_cast<const ulonglong2*>(vp1);
  kp0 += (size_t)64 * N_QKV; kp1 += (size_t)64 * N_QKV; vp0 += 64; vp1 += 64;
  *reinterpret_cast<ulonglong2*>(&Klds[0][ko0]) = rk0;
  *reinterpret_cast<ulonglong2*>(&Klds[0][ko1]) = rk1;
  *reinterpret_cast<ulonglong2*>(&Vlds[0][ko0]) = rv0;
  *reinterpret_cast<ulonglong2*>(&Vlds[0][ko1]) = rv1;
  rk0 = *reinterpret_cast<const ulonglong2*>(kp0);
  rk1 = *reinterpret_cast<const ulonglong2*>(kp1);
  rv0 = *reinterpret_cast<const ulonglong2*>(vp0);
  rv1 = *reinterpret_cast<const ulonglong2*>(vp1);
  kp0 += (size_t)64 * N_QKV; kp1 += (size_t)64 * N_QKV; vp0 += 64; vp1 += 64;
  __syncthreads();

  const int NT = T_SEQ / 64;   // 32
  for (int t = 0; t < NT; ++t) {
    int cur = t & 1;
    const unsigned short* Kc = Klds[cur];
    const unsigned short* Vc = Vlds[cur];

    // S = Q K^T (16 q-rows x 64 kv); Q pre-scaled (exp2 domain)
    f32x4 sc[4] = {};
    #pragma unroll
    for (int j = 0; j < 4; ++j)
      #pragma unroll
      for (int ks = 0; ks < 2; ++ks) {
        bf16x8 kf = *reinterpret_cast<const bf16x8*>(&Kc[(j * 16 + l15) * LDT + ks * 32 + l4 * 8]);
        sc[j] = mfma16(qf[ks], kf, sc[j]);
      }

    // P = exp2(S) -> per-wave LDS (bf16), conflict-free stride
    unsigned short* pw = &Plds[wid][0];
    #pragma unroll
    for (int j = 0; j < 4; ++j)
      #pragma unroll
      for (int r = 0; r < 4; ++r)
        pw[(l4 * 4 + r) * LDP + j * 16 + l15] = f2bf(exp2f(sc[j][r]));

    // O += P V ; L += P . 1
    #pragma unroll
    for (int ks = 0; ks < 2; ++ks) {
      bf16x8 pf = *reinterpret_cast<const bf16x8*>(&pw[l15 * LDP + ks * 32 + l4 * 8]);
      accL = mfma16(pf, ones, accL);
      #pragma unroll
      for (int dt = 0; dt < 4; ++dt) {
        int drow = dt * 16 + l15;
        bf16x8 vf = *reinterpret_cast<const bf16x8*>(&Vc[drow * LDT + (ks * 4 + l4) * 8]);
        accO[dt] = mfma16(pf, vf, accO[dt]);
      }
    }

    // stage tile t+1 into the other buffer (regs loaded iter t-1; latency already hidden)
    if (t + 1 < NT) {
      unsigned short* Kn = Klds[cur ^ 1];
      unsigned short* Vn = Vlds[cur ^ 1];
      *reinterpret_cast<ulonglong2*>(&Kn[ko0]) = rk0;
      *reinterpret_cast<ulonglong2*>(&Kn[ko1]) = rk1;
      *reinterpret_cast<ulonglong2*>(&Vn[ko0]) = rv0;
      *reinterpret_cast<ulonglong2*>(&Vn[ko1]) = rv1;
      if (t + 2 < NT) {   // issue loads for tile t+2
        rk0 = *reinterpret_cast<const ulonglong2*>(kp0);
        rk1 = *reinterpret_cast<const ulonglong2*>(kp1);
        rv0 = *reinterpret_cast<const ulonglong2*>(vp0);
        rv1 = *reinterpret_cast<const ulonglong2*>(vp1);
        kp0 += (size_t)64 * N_QKV; kp1 += (size_t)64 * N_QKV; vp0 += 64; vp1 += 64;
      }
    }
    __syncthreads();   // single barrier: RAW for buf[cur^1], WAR for buf[cur]
  }

  #pragma unroll
  for (int r = 0; r < 4; ++r) {
    float inv = 1.0f / accL[r];
    int rowq = q0 + wid * 16 + l4 * 4 + r;
    unsigned short* orow = o + (size_t)(b * T_SEQ + rowq) * DMODEL + h * 64;
    #pragma unroll
    for (int dt = 0; dt < 4; ++dt)
      orow[dt * 16 + l15] = f2bf(accO[dt][r] * inv);
  }
}

extern "C" void kernel_launch(void* const* d_in, const int* in_sizes, int n_in,
                              void* d_out, int out_size, void* d_ws, size_t ws_size,
                              hipStream_t stream) {
  const float* x     = (const float*)d_in[0];
  const float* gamma = (const float*)d_in[1];
  const float* beta  = (const float*)d_in[2];
  const float* w_qkv = (const float*)d_in[3];
  const float* w_out = (const float*)d_in[4];
  float* out = (float*)d_out;

  char* ws = (char*)d_ws;
  unsigned short* h_bf    = (unsigned short*)(ws);                       // 8 MB (dead after gemm1)
  unsigned short* vT      = (unsigned short*)(ws);                       // 8 MB, reuses h_bf region
  unsigned short* wqkvT   = (unsigned short*)(ws + 8388608);             // 6 MB
  unsigned short* woutT   = (unsigned short*)(ws + 14680064);            // 2 MB
  unsigned short* qkv     = (unsigned short*)(ws + 16777216);            // 24 MB
  unsigned short* attnout = (unsigned short*)(ws + 41943040);            // 8 MB

  ln_kernel<<<MROWS, 256, 0, stream>>>(x, gamma, beta, h_bf);
  transpose_cast<<<dim3(N_QKV / 32, DMODEL / 32), 256, 0, stream>>>(w_qkv, wqkvT, DMODEL, N_QKV);
  transpose_cast<<<dim3(DMODEL / 32, DMODEL / 32), 256, 0, stream>>>(w_out, woutT, DMODEL, DMODEL);
  gemm_bt_bf16<<<dim3(N_QKV / 128, MROWS / 128), 256, 0, stream>>>(h_bf, wqkvT, qkv, MROWS, N_QKV, DMODEL);
  vtrans_kernel<<<dim3(T_SEQ / 64, 2 * NHEAD), 256, 0, stream>>>(qkv, vT);   // overwrites h_bf (dead)
  attn_kernel<<<1024, 256, 0, stream>>>(qkv, vT, attnout);
  gemm_bt_f32res<<<dim3(DMODEL / 128, MROWS / 128), 256, 0, stream>>>(attnout, woutT, out, x, MROWS, DMODEL, DMODEL);
}

// Round 11
// 238.975 us; speedup vs baseline: 1.1248x; 1.1248x over previous
//
#include <hip/hip_runtime.h>

// Problem constants: B=2, T=2048, D=1024, H=16, DH=64
#define T_SEQ 2048
#define DMODEL 1024
#define NHEAD 16
#define MROWS 4096          // B*T
#define N_QKV 3072          // 3*D
#define LDT 72              // attn LDS row stride (elements), padded
#define LDG 64              // GEMM LDS row stride: LINEAR (global_load_lds requires contiguous dest)

typedef float f32x4 __attribute__((ext_vector_type(4)));
typedef __bf16 bf16_t;
typedef bf16_t bf16x8 __attribute__((ext_vector_type(8)));

// native f32->bf16 (RNE); compiler packs pairs into v_cvt_pk_bf16_f32 (m240)
__device__ __forceinline__ unsigned short f2bf(float f) {
  return __builtin_bit_cast(unsigned short, (__bf16)f);
}

__device__ __forceinline__ f32x4 mfma16(bf16x8 a, bf16x8 b, f32x4 c) {
  return __builtin_amdgcn_mfma_f32_16x16x32_bf16(a, b, c, 0, 0, 0);
}

// async global->LDS, 16B per lane. LDS dest must be wave-uniform base + lane*16,
// which our (row=tid>>3, col=(tid&7)*8) mapping onto a linear [*][64] tile satisfies.
__device__ __forceinline__ void gload_lds16(const unsigned short* gsrc, unsigned short* ldst) {
  __builtin_amdgcn_global_load_lds(
      (const __attribute__((address_space(1))) unsigned int*)gsrc,
      (__attribute__((address_space(3))) unsigned int*)ldst,
      16, 0, 0);
}

// ---------------- LayerNorm: x[4096][1024] f32 -> h bf16 ----------------
__global__ __launch_bounds__(256) void ln_kernel(const float* __restrict__ x,
    const float* __restrict__ g, const float* __restrict__ be,
    unsigned short* __restrict__ h) {
  int row = blockIdx.x;
  int t = threadIdx.x;
  float4 v = reinterpret_cast<const float4*>(x + (size_t)row * DMODEL)[t];
  float s = v.x + v.y + v.z + v.w;
  float s2 = v.x * v.x + v.y * v.y + v.z * v.z + v.w * v.w;
  for (int m = 1; m < 64; m <<= 1) { s += __shfl_xor(s, m, 64); s2 += __shfl_xor(s2, m, 64); }
  __shared__ float ls[4], ls2[4];
  int w = t >> 6;
  if ((t & 63) == 0) { ls[w] = s; ls2[w] = s2; }
  __syncthreads();
  s = ls[0] + ls[1] + ls[2] + ls[3];
  s2 = ls2[0] + ls2[1] + ls2[2] + ls2[3];
  float mean = s * (1.0f / DMODEL);
  float var = s2 * (1.0f / DMODEL) - mean * mean;   // biased var, matches jnp.var
  float rstd = rsqrtf(var + 1e-3f);
  float4 gv = reinterpret_cast<const float4*>(g)[t];
  float4 bv = reinterpret_cast<const float4*>(be)[t];
  ushort4 o;
  o.x = f2bf((v.x - mean) * rstd * gv.x + bv.x);
  o.y = f2bf((v.y - mean) * rstd * gv.y + bv.y);
  o.z = f2bf((v.z - mean) * rstd * gv.z + bv.z);
  o.w = f2bf((v.w - mean) * rstd * gv.w + bv.w);
  reinterpret_cast<ushort4*>(h + (size_t)row * DMODEL)[t] = o;
}

// ------- merged transpose+cast of both weights: w_qkv [1024][3072] and w_out [1024][1024] -------
__global__ __launch_bounds__(256) void transpose_cast2(const float* __restrict__ wqkv,
    const float* __restrict__ wout, unsigned short* __restrict__ outA,
    unsigned short* __restrict__ outB) {
  __shared__ float tile[32][33];
  int c0 = blockIdx.x * 32, r0 = blockIdx.y * 32;
  const float* in; unsigned short* out; int cols, cb;
  if (c0 < N_QKV) { in = wqkv; out = outA; cols = N_QKV; cb = c0; }
  else            { in = wout; out = outB; cols = DMODEL; cb = c0 - N_QKV; }
  int tx = threadIdx.x & 31, ty = threadIdx.x >> 5;
  #pragma unroll
  for (int i = 0; i < 4; ++i) {
    int r = ty + i * 8;
    tile[r][tx] = in[(size_t)(r0 + r) * cols + cb + tx];
  }
  __syncthreads();
  #pragma unroll
  for (int i = 0; i < 4; ++i) {
    int r = ty + i * 8;
    out[(size_t)(cb + r) * DMODEL + r0 + tx] = f2bf(tile[tx][r]);
  }
}

// ------------- GEMM1: qkv = h @ wqkvT^T; V-columns written TRANSPOSED to vT -------------
// 128x128 tile, BK=64, 4 waves, gload_lds16 staging. 1D grid 768, XCD-swizzled
// (768 = 96 per XCD x 8): consecutive s on one XCD share A-row panels in L2.
// For n0 >= 2048 (V region): acc[i][j][0..3] are 4 consecutive tokens -> pack
// into one 8B store at vT[b,h,d,t] (fuses the old vtrans kernel).
__global__ __launch_bounds__(256) void gemm_qkv(
    const unsigned short* __restrict__ A, const unsigned short* __restrict__ Bt,
    unsigned short* __restrict__ C, unsigned short* __restrict__ vT, int Kdim) {
  __shared__ alignas(16) unsigned short Alds[128 * LDG];
  __shared__ alignas(16) unsigned short Blds[128 * LDG];
  int wg = blockIdx.x;
  int s = (wg & 7) * 96 + (wg >> 3);     // bijective XCD swizzle (768 = 8*96)
  int bx = s % 24, by = s / 24;
  int m0 = by * 128, n0 = bx * 128;
  int tid = threadIdx.x;
  int wid = tid >> 6, lane = tid & 63;
  int l15 = lane & 15, l4 = lane >> 4;
  int wm = (wid >> 1) * 64, wn = (wid & 1) * 64;
  f32x4 acc[4][4] = {};
  int crow = tid >> 3, ccol = (tid & 7) * 8;
  for (int k0 = 0; k0 < Kdim; k0 += 64) {
    __syncthreads();
    #pragma unroll
    for (int it = 0; it < 4; ++it) {
      int row = crow + it * 32;
      gload_lds16(A + (size_t)(m0 + row) * Kdim + k0 + ccol, &Alds[row * LDG + ccol]);
      gload_lds16(Bt + (size_t)(n0 + row) * Kdim + k0 + ccol, &Blds[row * LDG + ccol]);
    }
    __syncthreads();
    #pragma unroll
    for (int ks = 0; ks < 2; ++ks) {
      int co = ks * 32 + l4 * 8;
      bf16x8 af[4], bfr[4];
      #pragma unroll
      for (int i = 0; i < 4; ++i)
        af[i] = *reinterpret_cast<const bf16x8*>(&Alds[(wm + i * 16 + l15) * LDG + co]);
      #pragma unroll
      for (int j = 0; j < 4; ++j)
        bfr[j] = *reinterpret_cast<const bf16x8*>(&Blds[(wn + j * 16 + l15) * LDG + co]);
      #pragma unroll
      for (int i = 0; i < 4; ++i)
        #pragma unroll
        for (int j = 0; j < 4; ++j)
          acc[i][j] = mfma16(af[i], bfr[j], acc[i][j]);
    }
  }
  if (n0 >= 2 * DMODEL) {
    // V region -> vT[b,h,d,t] = vT[(b*1024 + dcol)*2048 + t], 4 tokens packed per store
    int bq = m0 >> 11;                       // batch (whole block same batch)
    #pragma unroll
    for (int i = 0; i < 4; ++i)
      #pragma unroll
      for (int j = 0; j < 4; ++j) {
        int dcol = n0 + wn + j * 16 + l15 - 2 * DMODEL;     // h*64+d, 0..1023
        int t0 = (m0 & 2047) + wm + i * 16 + l4 * 4;        // token of r=0
        ushort4 pk;
        pk.x = f2bf(acc[i][j][0]); pk.y = f2bf(acc[i][j][1]);
        pk.z = f2bf(acc[i][j][2]); pk.w = f2bf(acc[i][j][3]);
        *reinterpret_cast<ushort4*>(vT + ((size_t)(bq * DMODEL + dcol) * T_SEQ + t0)) = pk;
      }
  } else {
    #pragma unroll
    for (int i = 0; i < 4; ++i)
      #pragma unroll
      for (int j = 0; j < 4; ++j)
        #pragma unroll
        for (int r = 0; r < 4; ++r) {
          int rr = m0 + wm + i * 16 + l4 * 4 + r;
          int cc = n0 + wn + j * 16 + l15;
          C[(size_t)rr * N_QKV + cc] = f2bf(acc[i][j][r]);
        }
  }
}

// ------------- GEMM + residual: out f32 = A @ woutT^T + x. 1D grid 256, XCD-swizzled -------------
__global__ __launch_bounds__(256) void gemm_bt_f32res(
    const unsigned short* __restrict__ A, const unsigned short* __restrict__ Bt,
    float* __restrict__ C, const float* __restrict__ resid, int Ndim, int Kdim) {
  __shared__ alignas(16) unsigned short Alds[128 * LDG];
  __shared__ alignas(16) unsigned short Blds[128 * LDG];
  int wg = blockIdx.x;
  int s = (wg & 7) * 32 + (wg >> 3);     // bijective XCD swizzle (256 = 8*32)
  int bx = s % 8, by = s / 8;
  int m0 = by * 128, n0 = bx * 128;
  int tid = threadIdx.x;
  int wid = tid >> 6, lane = tid & 63;
  int l15 = lane & 15, l4 = lane >> 4;
  int wm = (wid >> 1) * 64, wn = (wid & 1) * 64;
  f32x4 acc[4][4] = {};
  int crow = tid >> 3, ccol = (tid & 7) * 8;
  for (int k0 = 0; k0 < Kdim; k0 += 64) {
    __syncthreads();
    #pragma unroll
    for (int it = 0; it < 4; ++it) {
      int row = crow + it * 32;
      gload_lds16(A + (size_t)(m0 + row) * Kdim + k0 + ccol, &Alds[row * LDG + ccol]);
      gload_lds16(Bt + (size_t)(n0 + row) * Kdim + k0 + ccol, &Blds[row * LDG + ccol]);
    }
    __syncthreads();
    #pragma unroll
    for (int ks = 0; ks < 2; ++ks) {
      int co = ks * 32 + l4 * 8;
      bf16x8 af[4], bfr[4];
      #pragma unroll
      for (int i = 0; i < 4; ++i)
        af[i] = *reinterpret_cast<const bf16x8*>(&Alds[(wm + i * 16 + l15) * LDG + co]);
      #pragma unroll
      for (int j = 0; j < 4; ++j)
        bfr[j] = *reinterpret_cast<const bf16x8*>(&Blds[(wn + j * 16 + l15) * LDG + co]);
      #pragma unroll
      for (int i = 0; i < 4; ++i)
        #pragma unroll
        for (int j = 0; j < 4; ++j)
          acc[i][j] = mfma16(af[i], bfr[j], acc[i][j]);
    }
  }
  #pragma unroll
  for (int i = 0; i < 4; ++i)
    #pragma unroll
    for (int j = 0; j < 4; ++j)
      #pragma unroll
      for (int r = 0; r < 4; ++r) {
        size_t idx = (size_t)(m0 + wm + i * 16 + l4 * 4 + r) * Ndim + n0 + wn + j * 16 + l15;
        C[idx] = resid[idx] + acc[i][j][r];
      }
}

// ------------- fused flash attention, static-max softmax + T14, 32 q-rows/wave -------------
// (round-9 version: best measured, 78.4us) grid 512, XCD-decoded (4 bh per XCD).
// Each wave owns 32 q-rows; K/V fragments read from LDS once feed both row-tiles.
// P = exp2(S), denominator via ones-MFMA.
__global__ __launch_bounds__(256) void attn_kernel(const unsigned short* __restrict__ qkv,
    const unsigned short* __restrict__ vT, unsigned short* __restrict__ o) {
  int flat = blockIdx.x;
  int xcd = flat & 7, idx = flat >> 3;          // 64 idx per XCD
  int bh = xcd * 4 + (idx >> 4);                // 4 bh per XCD
  int q0 = (idx & 15) * 128;                    // 16 q-blocks of 128 rows
  int b = bh >> 4, h = bh & 15;
  int tid = threadIdx.x, wid = tid >> 6, lane = tid & 63;
  int l15 = lane & 15, l4 = lane >> 4;
  __shared__ alignas(16) unsigned short Klds[64 * LDT];     // K[j][d]
  __shared__ alignas(16) unsigned short Vt[64 * LDT];       // V^T[d][j]
  __shared__ alignas(16) unsigned short Plds[4][32 * LDT];  // per-wave P (32 rows)
  const unsigned short* base = qkv + (size_t)b * T_SEQ * N_QKV;
  const unsigned short* vbase = vT + (size_t)bh * 64 * T_SEQ;

  // Q fragments (2 row-tiles x 2 k-halves), pre-scaled by 0.125*log2(e) (exp2 domain)
  bf16x8 qf[2][2];
  #pragma unroll
  for (int i = 0; i < 2; ++i) {
    const unsigned short* qrow = base + (size_t)(q0 + wid * 32 + i * 16 + l15) * N_QKV + h * 64;
    qf[i][0] = *reinterpret_cast<const bf16x8*>(qrow + l4 * 8);
    qf[i][1] = *reinterpret_cast<const bf16x8*>(qrow + 32 + l4 * 8);
    #pragma unroll
    for (int e = 0; e < 8; ++e) {
      qf[i][0][e] = (__bf16)((float)qf[i][0][e] * 0.18033688f);
      qf[i][1][e] = (__bf16)((float)qf[i][1][e] * 0.18033688f);
    }
  }
  bf16x8 ones;
  #pragma unroll
  for (int e = 0; e < 8; ++e) ones[e] = (__bf16)1.0f;

  f32x4 accO[2][4] = {};
  f32x4 accL[2] = {};

  int crow = tid >> 3, ccol8 = tid & 7;
  const unsigned short* kp0 = base + (size_t)crow * N_QKV + DMODEL + h * 64 + ccol8 * 8;
  const unsigned short* kp1 = kp0 + (size_t)32 * N_QKV;
  const unsigned short* vp0 = vbase + (size_t)crow * T_SEQ + ccol8 * 8;
  const unsigned short* vp1 = vp0 + (size_t)32 * T_SEQ;
  unsigned short* kl0 = &Klds[crow * LDT + ccol8 * 8];
  unsigned short* kl1 = &Klds[(crow + 32) * LDT + ccol8 * 8];
  unsigned short* vl0 = &Vt[crow * LDT + ccol8 * 8];
  unsigned short* vl1 = &Vt[(crow + 32) * LDT + ccol8 * 8];

  // T14 prologue: tile 0 -> regs
  ulonglong2 rk0 = *reinterpret_cast<const ulonglong2*>(kp0);
  ulonglong2 rk1 = *reinterpret_cast<const ulonglong2*>(kp1);
  ulonglong2 rv0 = *reinterpret_cast<const ulonglong2*>(vp0);
  ulonglong2 rv1 = *reinterpret_cast<const ulonglong2*>(vp1);
  kp0 += (size_t)64 * N_QKV; kp1 += (size_t)64 * N_QKV;
  vp0 += 64; vp1 += 64;

  for (int kv0 = 0; kv0 < T_SEQ; kv0 += 64) {
    __syncthreads();           // previous iter's LDS reads complete
    *reinterpret_cast<ulonglong2*>(kl0) = rk0;
    *reinterpret_cast<ulonglong2*>(kl1) = rk1;
    *reinterpret_cast<ulonglong2*>(vl0) = rv0;
    *reinterpret_cast<ulonglong2*>(vl1) = rv1;
    if (kv0 + 64 < T_SEQ) {    // issue next tile's loads; land during compute below
      rk0 = *reinterpret_cast<const ulonglong2*>(kp0);
      rk1 = *reinterpret_cast<const ulonglong2*>(kp1);
      rv0 = *reinterpret_cast<const ulonglong2*>(vp0);
      rv1 = *reinterpret_cast<const ulonglong2*>(vp1);
      kp0 += (size_t)64 * N_QKV; kp1 += (size_t)64 * N_QKV;
      vp0 += 64; vp1 += 64;
    }
    __syncthreads();           // staged tile visible

    // S = Q K^T: kf read once, feeds both row-tiles
    f32x4 sc[2][4] = {};
    #pragma unroll
    for (int j = 0; j < 4; ++j)
      #pragma unroll
      for (int ks = 0; ks < 2; ++ks) {
        bf16x8 kf = *reinterpret_cast<const bf16x8*>(&Klds[(j * 16 + l15) * LDT + ks * 32 + l4 * 8]);
        sc[0][j] = mfma16(qf[0][ks], kf, sc[0][j]);
        sc[1][j] = mfma16(qf[1][ks], kf, sc[1][j]);
      }

    // P = exp2(S) -> LDS (bf16), per-wave region (32 rows)
    unsigned short* pw = &Plds[wid][0];
    #pragma unroll
    for (int i = 0; i < 2; ++i)
      #pragma unroll
      for (int j = 0; j < 4; ++j)
        #pragma unroll
        for (int r = 0; r < 4; ++r)
          pw[(i * 16 + l4 * 4 + r) * LDT + j * 16 + l15] = f2bf(exp2f(sc[i][j][r]));

    // O += P V ; L += P . 1 — vf read once per (dt,ks), feeds both row-tiles
    #pragma unroll
    for (int ks = 0; ks < 2; ++ks) {
      bf16x8 pf0 = *reinterpret_cast<const bf16x8*>(&pw[l15 * LDT + ks * 32 + l4 * 8]);
      bf16x8 pf1 = *reinterpret_cast<const bf16x8*>(&pw[(16 + l15) * LDT + ks * 32 + l4 * 8]);
      accL[0] = mfma16(pf0, ones, accL[0]);
      accL[1] = mfma16(pf1, ones, accL[1]);
      #pragma unroll
      for (int dt = 0; dt < 4; ++dt) {
        int drow = dt * 16 + l15;
        bf16x8 vf = *reinterpret_cast<const bf16x8*>(&Vt[drow * LDT + (ks * 4 + l4) * 8]);
        accO[0][dt] = mfma16(pf0, vf, accO[0][dt]);
        accO[1][dt] = mfma16(pf1, vf, accO[1][dt]);
      }
    }
  }

  #pragma unroll
  for (int i = 0; i < 2; ++i)
    #pragma unroll
    for (int r = 0; r < 4; ++r) {
      float inv = 1.0f / accL[i][r];
      int rowq = q0 + wid * 32 + i * 16 + l4 * 4 + r;
      unsigned short* orow = o + (size_t)(b * T_SEQ + rowq) * DMODEL + h * 64;
      #pragma unroll
      for (int dt = 0; dt < 4; ++dt)
        orow[dt * 16 + l15] = f2bf(accO[i][dt][r] * inv);
    }
}

extern "C" void kernel_launch(void* const* d_in, const int* in_sizes, int n_in,
                              void* d_out, int out_size, void* d_ws, size_t ws_size,
                              hipStream_t stream) {
  const float* x     = (const float*)d_in[0];
  const float* gamma = (const float*)d_in[1];
  const float* beta  = (const float*)d_in[2];
  const float* w_qkv = (const float*)d_in[3];
  const float* w_out = (const float*)d_in[4];
  float* out = (float*)d_out;

  char* ws = (char*)d_ws;
  unsigned short* h_bf    = (unsigned short*)(ws);                       // 8 MB; dead after gemm1
  unsigned short* attnout = (unsigned short*)(ws);                       // reuses h_bf slot
  unsigned short* wqkvT   = (unsigned short*)(ws + 8388608);             // 6 MB
  unsigned short* woutT   = (unsigned short*)(ws + 14680064);            // 2 MB
  unsigned short* qkv     = (unsigned short*)(ws + 16777216);            // 24 MB (V region unused)
  unsigned short* vT      = (unsigned short*)(ws + 41943040);            // 8 MB (written by gemm1)

  ln_kernel<<<MROWS, 256, 0, stream>>>(x, gamma, beta, h_bf);
  transpose_cast2<<<dim3((N_QKV + DMODEL) / 32, DMODEL / 32), 256, 0, stream>>>(
      w_qkv, w_out, wqkvT, woutT);
  gemm_qkv<<<768, 256, 0, stream>>>(h_bf, wqkvT, qkv, vT, DMODEL);
  attn_kernel<<<512, 256, 0, stream>>>(qkv, vT, attnout);
  gemm_bt_f32res<<<256, 256, 0, stream>>>(attnout, woutT, out, x, DMODEL, DMODEL);
}